// Round 14
// baseline (337.328 us; speedup 1.0000x reference)
//
#include <hip/hip_runtime.h>
#include <hip/hip_bf16.h>
#include <math.h>

#define NR 8192
#define DD 1024
#define BAND 4096

typedef __attribute__((ext_vector_type(8))) short bf16x8;
typedef __attribute__((ext_vector_type(4))) float f32x4;

struct u16x4 { unsigned short x, y, z, w; };

__device__ __forceinline__ unsigned short f2bf(float v) {
    __hip_bfloat16 h = __float2bfloat16(v);
    return *(unsigned short*)&h;
}
__device__ __forceinline__ float bf2f(unsigned short u) {
    __hip_bfloat16 h = *(__hip_bfloat16*)&u;
    return __bfloat162float(h);
}

// async global->LDS: 16B/lane; LDS dest = wave-uniform base + lane*16
__device__ __forceinline__ void dma16(const void* g, void* l) {
    __builtin_amdgcn_global_load_lds(
        (const __attribute__((address_space(1))) unsigned int*)g,
        (__attribute__((address_space(3))) unsigned int*)l, 16, 0, 0);
}

// ---------------------------------------------------------------------------
// prep_xsplit: X fp32 -> xpack rows [hi 2048B | lo 2048B]
// ---------------------------------------------------------------------------
__global__ __launch_bounds__(256) void prep_xsplit(const float* __restrict__ X,
                                                   char* __restrict__ xpack) {
    const int idx  = blockIdx.x * 256 + threadIdx.x;
    const int base = idx * 4;
    const int r = base >> 10;
    const int c = base & 1023;
    float4 v = *(const float4*)(X + (size_t)base);
    u16x4 hi, lo;
    hi.x = f2bf(v.x); lo.x = f2bf(v.x - bf2f(hi.x));
    hi.y = f2bf(v.y); lo.y = f2bf(v.y - bf2f(hi.y));
    hi.z = f2bf(v.z); lo.z = f2bf(v.z - bf2f(hi.z));
    hi.w = f2bf(v.w); lo.w = f2bf(v.w - bf2f(hi.w));
    *(u16x4*)(xpack + (size_t)r * 4096 + c * 2)        = hi;
    *(u16x4*)(xpack + (size_t)r * 4096 + 2048 + c * 2) = lo;
}

// ---------------------------------------------------------------------------
// prep_wt: W[k][n] fp32 -> WT hi/lo bf16 [n][k]
// ---------------------------------------------------------------------------
__global__ __launch_bounds__(256) void prep_wt(const float* __restrict__ W,
                                               unsigned short* __restrict__ WThi,
                                               unsigned short* __restrict__ WTlo) {
    __shared__ float t[64][65];
    const int k0 = blockIdx.x * 64;
    const int n0 = blockIdx.y * 64;
    const int tid = threadIdx.x;
    const int tr = tid >> 6;
    const int tc = tid & 63;
#pragma unroll
    for (int rep = 0; rep < 16; ++rep) {
        int r = rep * 4 + tr;
        t[r][tc] = W[(size_t)(k0 + r) * DD + n0 + tc];
    }
    __syncthreads();
#pragma unroll
    for (int rep = 0; rep < 16; ++rep) {
        int c = rep * 4 + tr;
        float v = t[tc][c];
        unsigned short hi = f2bf(v);
        WThi[(size_t)(n0 + c) * DD + k0 + tc] = hi;
        WTlo[(size_t)(n0 + c) * DD + k0 + tc] = f2bf(v - bf2f(hi));
    }
}

// ---------------------------------------------------------------------------
// proj_mfma: C[128m x 256n] = X.W via 3-product split-bf16 MFMA,
// 2-phase dbuf gload_lds, BK=32.  SWZ=1: XCD-aware block decode (1-D grid
// of 256; XCD x pins WT n-slice (x>>1) in its L2).  SWZ=0: control (4,64).
// ---------------------------------------------------------------------------
template <int MODE, int SWZ>
__global__ __launch_bounds__(512, 2) void proj_mfma(
        const char* __restrict__ xpk,
        const unsigned short* __restrict__ WThi,
        const unsigned short* __restrict__ WTlo,
        char* __restrict__ qpack,
        unsigned short* __restrict__ khi,
        unsigned short* __restrict__ klo) {
    __shared__ __align__(128) char lds[98304];   // 2 x 48KB: [A 16K | B 32K]

    const int tid = threadIdx.x;
    const int l   = tid & 63;
    const int w   = tid >> 6;
    const int l15 = l & 15;
    const int lk  = l >> 4;
    const int swz = l15 & 7;
    const int wm  = w >> 2;
    const int wn  = w & 3;

    int bxx, byy;
    if (SWZ) {
        int bid = blockIdx.x;           // 0..255
        int xcd = bid & 7;
        int i   = bid >> 3;             // 0..31
        bxx = xcd >> 1;                 // n-block 0..3 (pinned per XCD pair)
        byy = (i << 1) | (xcd & 1);     // m-block 0..63
    } else {
        bxx = blockIdx.x;
        byy = blockIdx.y;
    }
    const int n0 = bxx * 256;
    const int m0 = byy * 128;

    const char* src[6];
    int ldst[6];
#pragma unroll
    for (int d = 0; d < 2; ++d) {
        int s = d * 512 + tid;
        int r = s >> 3, phys = s & 7;
        int j = phys ^ (r & 7);
        src[d]  = xpk + (size_t)(m0 + r) * 4096 + (j >> 2) * 2048 + (j & 3) * 16;
        ldst[d] = d * 8192 + tid * 16;
    }
#pragma unroll
    for (int d = 2; d < 6; ++d) {
        int s = (d - 2) * 512 + tid;
        int r = s >> 3, phys = s & 7;
        int j = phys ^ (r & 7);
        const unsigned short* base = (j >> 2) ? WTlo : WThi;
        src[d]  = (const char*)(base + (size_t)(n0 + r) * DD + (j & 3) * 8);
        ldst[d] = 16384 + (d - 2) * 8192 + tid * 16;
    }

    f32x4 acc[4][4];
#pragma unroll
    for (int mr = 0; mr < 4; ++mr)
#pragma unroll
        for (int nf = 0; nf < 4; ++nf) acc[mr][nf] = f32x4{0.f, 0.f, 0.f, 0.f};

#pragma unroll
    for (int d = 0; d < 6; ++d) dma16(src[d], &lds[ldst[d]]);
    __syncthreads();

    for (int t = 0; t < 32; ++t) {
        const int cur = t & 1;
        if (t < 31) {
            const int nb = cur ^ 1;
#pragma unroll
            for (int d = 0; d < 6; ++d)
                dma16(src[d] + (t + 1) * 64, &lds[nb * 49152 + ldst[d]]);
        }
        const char* AB = &lds[cur * 49152];

        bf16x8 bh[4], bl[4];
#pragma unroll
        for (int nf = 0; nf < 4; ++nf) {
            int row = wn * 64 + nf * 16 + l15;
            bh[nf] = *(const bf16x8*)&AB[16384 + row * 128 + ((lk ^ swz) << 4)];
            bl[nf] = *(const bf16x8*)&AB[16384 + row * 128 + (((lk ^ 4) ^ swz) << 4)];
        }
        bf16x8 ah[4], al[4];
#pragma unroll
        for (int i = 0; i < 4; ++i) {
            int row = wm * 64 + i * 16 + l15;
            ah[i] = *(const bf16x8*)&AB[row * 128 + ((lk ^ swz) << 4)];
            al[i] = *(const bf16x8*)&AB[row * 128 + (((lk ^ 4) ^ swz) << 4)];
        }
        __builtin_amdgcn_s_setprio(1);
#pragma unroll
        for (int mr = 0; mr < 4; ++mr)
#pragma unroll
            for (int nf = 0; nf < 4; ++nf) {
                acc[mr][nf] = __builtin_amdgcn_mfma_f32_16x16x32_bf16(ah[mr], bh[nf], acc[mr][nf], 0, 0, 0);
                acc[mr][nf] = __builtin_amdgcn_mfma_f32_16x16x32_bf16(al[mr], bh[nf], acc[mr][nf], 0, 0, 0);
                acc[mr][nf] = __builtin_amdgcn_mfma_f32_16x16x32_bf16(ah[mr], bl[nf], acc[mr][nf], 0, 0, 0);
            }
        __builtin_amdgcn_s_setprio(0);
        __syncthreads();
    }

#pragma unroll
    for (int mr = 0; mr < 4; ++mr)
#pragma unroll
        for (int g = 0; g < 4; ++g) {
            int row = m0 + wm * 64 + mr * 16 + lk * 4 + g;
#pragma unroll
            for (int nf = 0; nf < 4; ++nf) {
                int col = n0 + wn * 64 + nf * 16 + l15;
                float v = acc[mr][nf][g];
                unsigned short hi = f2bf(v);
                unsigned short lo = f2bf(v - bf2f(hi));
                if (MODE == 0) {
                    *(unsigned short*)(qpack + (size_t)row * 4096 + col * 2)        = hi;
                    *(unsigned short*)(qpack + (size_t)row * 4096 + 2048 + col * 2) = lo;
                } else {
                    khi[(size_t)row * DD + col] = hi;
                    klo[(size_t)row * DD + col] = lo;
                }
            }
        }
}

// ---------------------------------------------------------------------------
// sgemmc core (shared body): COARSE T = Qh.Khi^T * scale - tilemax, bf16.
// 2-phase dbuf gload_lds, BK=64, 16 steps.  kvb/qb passed in by wrappers.
// ---------------------------------------------------------------------------
__device__ __forceinline__ void sgemmc_body(const char* __restrict__ qpk,
                                            const unsigned short* __restrict__ Khi,
                                            unsigned short* __restrict__ Tb,
                                            float* __restrict__ mtile,
                                            int band, int kvb, int qb) {
    __shared__ __align__(128) char lds[131072];   // 2 x 64KB: [A 32K | B 32K]
    __shared__ float rmax[256][4];

    const int tid = threadIdx.x;
    const int l   = tid & 63;
    const int w   = tid >> 6;
    const int l15 = l & 15;
    const int lk  = l >> 4;
    const int swz = l15 & 7;
    const int wm  = w >> 2;          // 0..1  q strip (128)
    const int wn  = w & 3;           // 0..3  kv strip (64)

    const int kv0   = kvb * 256;
    const int trow0 = qb * 256;
    const size_t qrow0 = (size_t)band * BAND + trow0;

    const char* src[8];
    int ldst[8];
#pragma unroll
    for (int d = 0; d < 4; ++d) {          // A = Qh rows
        int s = d * 512 + tid;
        int r = s >> 3, phys = s & 7;
        int j = phys ^ (r & 7);
        src[d]  = qpk + (qrow0 + r) * 4096 + j * 16;
        ldst[d] = d * 8192 + tid * 16;
    }
#pragma unroll
    for (int d = 4; d < 8; ++d) {          // B = Khi rows
        int s = (d - 4) * 512 + tid;
        int r = s >> 3, phys = s & 7;
        int j = phys ^ (r & 7);
        src[d]  = (const char*)(Khi + (size_t)(kv0 + r) * 1024) + j * 16;
        ldst[d] = 32768 + (d - 4) * 8192 + tid * 16;
    }

    f32x4 acc[8][4];
#pragma unroll
    for (int mr = 0; mr < 8; ++mr)
#pragma unroll
        for (int nf = 0; nf < 4; ++nf) acc[mr][nf] = f32x4{0.f, 0.f, 0.f, 0.f};

#pragma unroll
    for (int d = 0; d < 8; ++d) dma16(src[d], &lds[ldst[d]]);
    __syncthreads();

    for (int t = 0; t < 16; ++t) {
        const int cur = t & 1;
        if (t < 15) {
            const int nb = cur ^ 1;
#pragma unroll
            for (int d = 0; d < 8; ++d)
                dma16(src[d] + (t + 1) * 128, &lds[nb * 65536 + ldst[d]]);
        }
        const char* AB = &lds[cur * 65536];

        bf16x8 bh[4], bh2[4];
#pragma unroll
        for (int nf = 0; nf < 4; ++nf) {
            int row = wn * 64 + nf * 16 + l15;
            bh[nf]  = *(const bf16x8*)&AB[32768 + row * 128 + ((lk ^ swz) << 4)];
            bh2[nf] = *(const bf16x8*)&AB[32768 + row * 128 + (((lk ^ 4) ^ swz) << 4)];
        }
#pragma unroll
        for (int half = 0; half < 2; ++half) {
            bf16x8 ah[4], ah2[4];
#pragma unroll
            for (int i = 0; i < 4; ++i) {
                int row = wm * 128 + (half * 4 + i) * 16 + l15;
                ah[i]  = *(const bf16x8*)&AB[row * 128 + ((lk ^ swz) << 4)];
                ah2[i] = *(const bf16x8*)&AB[row * 128 + (((lk ^ 4) ^ swz) << 4)];
            }
            __builtin_amdgcn_s_setprio(1);
#pragma unroll
            for (int i = 0; i < 4; ++i) {
                int mr = half * 4 + i;
#pragma unroll
                for (int nf = 0; nf < 4; ++nf) {
                    acc[mr][nf] = __builtin_amdgcn_mfma_f32_16x16x32_bf16(ah[i],  bh[nf],  acc[mr][nf], 0, 0, 0);
                    acc[mr][nf] = __builtin_amdgcn_mfma_f32_16x16x32_bf16(ah2[i], bh2[nf], acc[mr][nf], 0, 0, 0);
                }
            }
            __builtin_amdgcn_s_setprio(0);
        }
        __syncthreads();
    }

#pragma unroll
    for (int mr = 0; mr < 8; ++mr)
#pragma unroll
        for (int nf = 0; nf < 4; ++nf) acc[mr][nf] *= 0.03125f;

#pragma unroll
    for (int mr = 0; mr < 8; ++mr)
#pragma unroll
        for (int g = 0; g < 4; ++g) {
            float m = fmaxf(fmaxf(acc[mr][0][g], acc[mr][1][g]),
                            fmaxf(acc[mr][2][g], acc[mr][3][g]));
#pragma unroll
            for (int msk = 1; msk <= 8; msk <<= 1)
                m = fmaxf(m, __shfl_xor(m, msk, 64));
            if (l15 == 0) rmax[wm * 128 + mr * 16 + lk * 4 + g][wn] = m;
        }
    __syncthreads();

#pragma unroll
    for (int mr = 0; mr < 8; ++mr)
#pragma unroll
        for (int g = 0; g < 4; ++g) {
            int r = wm * 128 + mr * 16 + lk * 4 + g;
            float4 v = *(const float4*)&rmax[r][0];
            float mt = fmaxf(fmaxf(v.x, v.y), fmaxf(v.z, v.w));
            if (wn == 0 && l15 == 0)
                mtile[(size_t)(trow0 + r) * 32 + kvb] = mt;
#pragma unroll
            for (int nf = 0; nf < 4; ++nf)
                Tb[(size_t)(trow0 + r) * 8192 + kv0 + wn * 64 + nf * 16 + l15] =
                    f2bf(acc[mr][nf][g] - mt);
        }
}

// swizzled: 1-D grid 512; XCD x owns kv-panels [4x,4x+4) (B 2MB L2-pinned)
__global__ __launch_bounds__(512, 2) void sgemmc_swz(const char* __restrict__ qpk,
                                                     const unsigned short* __restrict__ Khi,
                                                     unsigned short* __restrict__ Tb,
                                                     float* __restrict__ mtile,
                                                     int band) {
    const int bid = blockIdx.x;
    const int xcd = bid & 7;
    const int i   = bid >> 3;               // 0..63
    const int kvb = (xcd << 2) | (i & 3);   // 0..31
    const int qb  = i >> 2;                 // 0..15
    sgemmc_body(qpk, Khi, Tb, mtile, band, kvb, qb);
}

// control: original (32,16) grid
__global__ __launch_bounds__(512, 2) void sgemmc_ctl(const char* __restrict__ qpk,
                                                     const unsigned short* __restrict__ Khi,
                                                     unsigned short* __restrict__ Tb,
                                                     float* __restrict__ mtile,
                                                     int band) {
    sgemmc_body(qpk, Khi, Tb, mtile, band, blockIdx.x, blockIdx.y);
}

// ---------------------------------------------------------------------------
// softargmax (R13 proven): candidates = coarse > rowmax - DELTA; exact fp32
// fixup dots; gather-blend fp32 X rows into d_out.
// ---------------------------------------------------------------------------
#define DELTA 14.0f
#define MAXC  32

__global__ __launch_bounds__(256) void softargmax(
        const unsigned short* __restrict__ Tb,
        const float* __restrict__ mtile,
        const char* __restrict__ qpk,
        const unsigned short* __restrict__ Khi,
        const unsigned short* __restrict__ Klo,
        const float* __restrict__ X,
        float* __restrict__ outp,
        int band) {
    __shared__ int   scnt;
    __shared__ int   scol[MAXC];
    __shared__ float sred[4];
    __shared__ float eL[MAXC];

    const int r   = blockIdx.x;
    const size_t R = (size_t)band * BAND + r;
    const int tid = threadIdx.x;
    const int l   = tid & 63;
    const int w   = tid >> 6;

    if (tid == 0) scnt = 0;

    const unsigned short* trow = Tb + (size_t)r * 8192;
    const float* mrow = mtile + (size_t)r * 32;

    bf16x8 tv[4];
    float  mt[4];
#pragma unroll
    for (int j = 0; j < 4; ++j) {
        int q = j * 256 + tid;
        tv[j] = *(const bf16x8*)(trow + q * 8);
        mt[j] = mrow[q >> 5];
    }

    float lm = -3.0e38f;
#pragma unroll
    for (int j = 0; j < 4; ++j)
#pragma unroll
        for (int e = 0; e < 8; ++e)
            lm = fmaxf(lm, bf2f((unsigned short)tv[j][e]) + mt[j]);
#pragma unroll
    for (int msk = 1; msk <= 32; msk <<= 1)
        lm = fmaxf(lm, __shfl_xor(lm, msk, 64));
    if (l == 0) sred[w] = lm;
    __syncthreads();
    const float mc = fmaxf(fmaxf(sred[0], sred[1]), fmaxf(sred[2], sred[3]));

    const float thresh = mc - DELTA;
#pragma unroll
    for (int j = 0; j < 4; ++j)
#pragma unroll
        for (int e = 0; e < 8; ++e) {
            float v = bf2f((unsigned short)tv[j][e]) + mt[j];
            if (v > thresh) {
                int i = atomicAdd(&scnt, 1);
                if (i < MAXC) scol[i] = (j * 256 + tid) * 8 + e;
            }
        }
    __syncthreads();
    const int n = (scnt < MAXC) ? scnt : MAXC;

    u16x4 qh4 = *(const u16x4*)(qpk + R * 4096 + tid * 8);
    u16x4 ql4 = *(const u16x4*)(qpk + R * 4096 + 2048 + tid * 8);
    float qv0 = bf2f(qh4.x) + bf2f(ql4.x);
    float qv1 = bf2f(qh4.y) + bf2f(ql4.y);
    float qv2 = bf2f(qh4.z) + bf2f(ql4.z);
    float qv3 = bf2f(qh4.w) + bf2f(ql4.w);

    for (int c = 0; c < n; ++c) {
        int col = scol[c];
        u16x4 kh4 = *(const u16x4*)(Khi + (size_t)col * 1024 + tid * 4);
        u16x4 kl4 = *(const u16x4*)(Klo + (size_t)col * 1024 + tid * 4);
        float part = qv0 * (bf2f(kh4.x) + bf2f(kl4.x))
                   + qv1 * (bf2f(kh4.y) + bf2f(kl4.y))
                   + qv2 * (bf2f(kh4.z) + bf2f(kl4.z))
                   + qv3 * (bf2f(kh4.w) + bf2f(kl4.w));
#pragma unroll
        for (int msk = 1; msk <= 32; msk <<= 1)
            part += __shfl_xor(part, msk, 64);
        if (l == 0) sred[w] = part;
        __syncthreads();
        if (tid == 0)
            eL[c] = (sred[0] + sred[1] + sred[2] + sred[3]) * 0.03125f;
        __syncthreads();
    }

    float m = -3.0e38f;
    for (int c = 0; c < n; ++c) m = fmaxf(m, eL[c]);
    float ls = 0.f;
    for (int c = 0; c < n; ++c) ls += __expf(eL[c] - m);
    const float inv = 1.0f / ls;

    float4 o = make_float4(0.f, 0.f, 0.f, 0.f);
    for (int c = 0; c < n; ++c) {
        float wgt = __expf(eL[c] - m) * inv;
        float4 xv = *(const float4*)(X + (size_t)scol[c] * 1024 + tid * 4);
        o.x += wgt * xv.x;
        o.y += wgt * xv.y;
        o.z += wgt * xv.z;
        o.w += wgt * xv.w;
    }
    *(float4*)(outp + R * 1024 + tid * 4) = o;
}

extern "C" void kernel_launch(void* const* d_in, const int* in_sizes, int n_in,
                              void* d_out, int out_size, void* d_ws, size_t ws_size,
                              hipStream_t stream) {
    const float* X  = (const float*)d_in[0];
    const float* Wq = (const float*)d_in[1];
    const float* Wk = (const float*)d_in[2];

    char* qpack = (char*)d_out;                     // [Qhi|Qlo] 4KB/row

    unsigned short* khi = (unsigned short*)d_ws;                 // 16 MiB
    unsigned short* klo = khi + (size_t)NR * DD;                 // 16 MiB
    unsigned short* xt  = klo + (size_t)NR * DD;                 // 16 MiB (unused)
    unsigned short* Tb  = xt + (size_t)DD * NR;                  // 64 MiB
    float* mtile        = (float*)(Tb + (size_t)BAND * NR);      // 512 KiB
    float* rinv         = mtile + (size_t)BAND * 32;             // (unused)
    unsigned short* Opart = (unsigned short*)(rinv + BAND);      // region reused

    char* xpack = (char*)Opart;
    unsigned short* wtq_hi = Tb;
    unsigned short* wtq_lo = Tb + (size_t)DD * DD;
    unsigned short* wtk_hi = Tb + (size_t)2 * DD * DD;
    unsigned short* wtk_lo = Tb + (size_t)3 * DD * DD;

    prep_xsplit<<<NR * DD / 4 / 256, 256, 0, stream>>>(X, xpack);
    prep_wt<<<dim3(16, 16), 256, 0, stream>>>(Wq, wtq_hi, wtq_lo);
    prep_wt<<<dim3(16, 16), 256, 0, stream>>>(Wk, wtk_hi, wtk_lo);

    // A/B: Q-proj swizzled (1-D grid), K-proj control (2-D grid)
    proj_mfma<0, 1><<<256, 512, 0, stream>>>(
        xpack, wtq_hi, wtq_lo, qpack, nullptr, nullptr);
    proj_mfma<1, 0><<<dim3(DD / 256, NR / 128), 512, 0, stream>>>(
        xpack, wtk_hi, wtk_lo, nullptr, khi, klo);

    for (int band = 0; band < 2; ++band) {
        // A/B: band 0 XCD-swizzled, band 1 control
        if (band == 0)
            sgemmc_swz<<<512, 512, 0, stream>>>(qpack, khi, Tb, mtile, band);
        else
            sgemmc_ctl<<<dim3(NR / 256, BAND / 256), 512, 0, stream>>>(
                qpack, khi, Tb, mtile, band);
        softargmax<<<BAND, 256, 0, stream>>>(
            Tb, mtile, qpack, khi, klo, X, (float*)d_out, band);
    }
}